// Round 10
// baseline (429.591 us; speedup 1.0000x reference)
//
#include <hip/hip_runtime.h>

typedef unsigned short u16;
typedef u16 u16x8 __attribute__((ext_vector_type(8)));
typedef u16 u16x4 __attribute__((ext_vector_type(4)));
typedef __bf16 bf16x8 __attribute__((ext_vector_type(8)));
typedef float f32x4 __attribute__((ext_vector_type(4)));

__device__ __forceinline__ u16 f2bf(float x) {
  unsigned u = __builtin_bit_cast(unsigned, x);
  u = (u + 0x7FFFu + ((u >> 16) & 1u)) >> 16;
  return (u16)u;
}

#define GLOAD16(gp, lp)                                                        \
  __builtin_amdgcn_global_load_lds(                                            \
      (const __attribute__((address_space(1))) unsigned int*)(gp),             \
      (__attribute__((address_space(3))) unsigned int*)(lp), 16, 0, 0)

// ---------------- f32 -> bf16 convert (vectorized) ----------------
__global__ __launch_bounds__(256) void k_cvt(const float* __restrict__ in, u16* __restrict__ out, int n4) {
  int i = blockIdx.x * 256 + threadIdx.x;
  if (i >= n4) return;
  float4 v = ((const float4*)in)[i];
  u16x4 o;
  o[0] = f2bf(v.x); o[1] = f2bf(v.y); o[2] = f2bf(v.z); o[3] = f2bf(v.w);
  ((u16x4*)out)[i] = o;
}

// ---------------- f32 -> bf16 convert + transpose: out[c][r] = in[r][c], out row stride R ----------------
__global__ __launch_bounds__(256) void k_cvt_t(const float* __restrict__ in, u16* __restrict__ out, int R, int C) {
  __shared__ u16 t[64][72];
  int c0 = blockIdx.x * 64, r0 = blockIdx.y * 64;
  int tid = threadIdx.x;
  int rl = tid >> 2;          // 0..63
  int cl0 = (tid & 3) * 16;   // 0,16,32,48
#pragma unroll
  for (int j = 0; j < 4; ++j) {
    float4 v = *(const float4*)&in[(size_t)(r0 + rl) * C + c0 + cl0 + j * 4];
    t[rl][cl0 + j * 4 + 0] = f2bf(v.x);
    t[rl][cl0 + j * 4 + 1] = f2bf(v.y);
    t[rl][cl0 + j * 4 + 2] = f2bf(v.z);
    t[rl][cl0 + j * 4 + 3] = f2bf(v.w);
  }
  __syncthreads();
  int cr = tid >> 2;          // out row (c) 0..63
  int s0 = (tid & 3) * 16;    // r offset
  __align__(16) u16 tmp[16];
#pragma unroll
  for (int k = 0; k < 16; ++k) tmp[k] = t[s0 + k][cr];
  *(u16x8*)&out[(size_t)(c0 + cr) * R + r0 + s0]     = *(u16x8*)&tmp[0];
  *(u16x8*)&out[(size_t)(c0 + cr) * R + r0 + s0 + 8] = *(u16x8*)&tmp[8];
}

// ---------------- bf16 GEMM: C = A(MxK) * B(KxN), Bt given as N-major (NxK). 128x128 tile, BK=64 ----------------
template <bool F32OUT>
__global__ __launch_bounds__(256) void k_gemm(const u16* __restrict__ A, const u16* __restrict__ Bt,
                                              void* __restrict__ Cout, int M, int N, int K) {
  __shared__ __align__(16) u16 lA[128 * 64];
  __shared__ __align__(16) u16 lB[128 * 64];
  int m0 = blockIdx.x * 128, n0 = blockIdx.y * 128;
  int tid = threadIdx.x;
  int wid = tid >> 6, lane = tid & 63;
  int fr = lane & 15, fg = lane >> 4;
  int wm = (wid & 1) * 64, wn = (wid >> 1) * 64;
  int srow = tid >> 3, scu = (tid & 7) * 8;
  f32x4 acc[4][4] = {};
  const int nk = K >> 6;
  for (int kt = 0; kt < nk; ++kt) {
    int k0 = kt << 6;
#pragma unroll
    for (int r = 0; r < 4; ++r) {
      int row = srow + r * 32;
      int swz = scu ^ ((row & 7) << 3);
      GLOAD16(&A[(size_t)(m0 + row) * K + k0 + swz],  &lA[row * 64 + scu]);
      GLOAD16(&Bt[(size_t)(n0 + row) * K + k0 + swz], &lB[row * 64 + scu]);
    }
    __syncthreads();
#pragma unroll
    for (int kh = 0; kh < 2; ++kh) {
      bf16x8 af[4], bf[4];
#pragma unroll
      for (int mi = 0; mi < 4; ++mi) {
        int row = wm + mi * 16 + fr;
        af[mi] = *(const bf16x8*)&lA[row * 64 + ((kh * 32 + fg * 8) ^ ((row & 7) << 3))];
      }
#pragma unroll
      for (int ni = 0; ni < 4; ++ni) {
        int row = wn + ni * 16 + fr;
        bf[ni] = *(const bf16x8*)&lB[row * 64 + ((kh * 32 + fg * 8) ^ ((row & 7) << 3))];
      }
#pragma unroll
      for (int mi = 0; mi < 4; ++mi)
#pragma unroll
        for (int ni = 0; ni < 4; ++ni)
          acc[mi][ni] = __builtin_amdgcn_mfma_f32_16x16x32_bf16(af[mi], bf[ni], acc[mi][ni], 0, 0, 0);
    }
    __syncthreads();
  }
#pragma unroll
  for (int mi = 0; mi < 4; ++mi)
#pragma unroll
    for (int ni = 0; ni < 4; ++ni)
#pragma unroll
      for (int r = 0; r < 4; ++r) {
        int row = m0 + wm + mi * 16 + fg * 4 + r;
        int col = n0 + wn + ni * 16 + fr;
        float v = acc[mi][ni][r];
        if (F32OUT) ((float*)Cout)[(size_t)row * N + col] = v;
        else        ((u16*)Cout)[(size_t)row * N + col] = f2bf(v);
      }
}

// ---------------- RoPE on Q (with 1/sqrt(HD) pre-scale) and K; writes head-major layouts ----------------
__global__ __launch_bounds__(256) void k_rope(const u16* __restrict__ qkv, const float* __restrict__ fc,
                                              const float* __restrict__ fs, u16* __restrict__ Qr,
                                              u16* __restrict__ Kr) {
  int row = blockIdx.x;           // b*2048 + s
  int b = row >> 11, s = row & 2047;
  int tid = threadIdx.x;
  float4 c4 = *(const float4*)&fc[s * 64 + (tid & 15) * 4];
  float4 s4 = *(const float4*)&fs[s * 64 + (tid & 15) * 4];
  float cc[4] = {c4.x, c4.y, c4.z, c4.w};
  float ss[4] = {s4.x, s4.y, s4.z, s4.w};
  {
    bf16x8 v = *(const bf16x8*)&qkv[(size_t)row * 4096 + tid * 8];
    bf16x8 o;
    const float qs = 0.08838834764831845f;  // 1/sqrt(128)
#pragma unroll
    for (int j = 0; j < 4; ++j) {
      float e = (float)v[2 * j], od = (float)v[2 * j + 1];
      o[2 * j]     = (__bf16)((e * cc[j] - od * ss[j]) * qs);
      o[2 * j + 1] = (__bf16)((e * ss[j] + od * cc[j]) * qs);
    }
    int h = tid >> 4, d0 = (tid & 15) * 8;
    *(bf16x8*)&Qr[(((size_t)(b * 16 + h)) * 2048 + s) * 128 + d0] = o;
  }
  if (tid < 128) {
    bf16x8 v = *(const bf16x8*)&qkv[(size_t)row * 4096 + 2048 + tid * 8];
    bf16x8 o;
#pragma unroll
    for (int j = 0; j < 4; ++j) {
      float e = (float)v[2 * j], od = (float)v[2 * j + 1];
      o[2 * j]     = (__bf16)(e * cc[j] - od * ss[j]);
      o[2 * j + 1] = (__bf16)(e * ss[j] + od * cc[j]);
    }
    int hk = tid >> 4, d0 = (tid & 15) * 8;
    *(bf16x8*)&Kr[(((size_t)(b * 8 + hk)) * 2048 + s) * 128 + d0] = o;
  }
}

// ---------------- V transpose: Vt[b][hk][d][s] = qkv[b*S+s][3072 + hk*128 + d] ----------------
__global__ __launch_bounds__(256) void k_vtrans(const u16* __restrict__ qkv, u16* __restrict__ Vt) {
  __shared__ u16 t[64][72];
  int dt = blockIdx.x, st = blockIdx.y, bh = blockIdx.z;
  int b = bh >> 3, hk = bh & 7;
  int s0 = st * 64, d0 = dt * 64;
  int tid = threadIdx.x;
  int rl = tid >> 3, cs = (tid & 7) * 8;
#pragma unroll
  for (int rnd = 0; rnd < 2; ++rnd) {
    int srow = rl + rnd * 32;
    u16x8 v = *(const u16x8*)&qkv[(size_t)(b * 2048 + s0 + srow) * 4096 + 3072 + hk * 128 + d0 + cs];
#pragma unroll
    for (int k = 0; k < 8; ++k) t[srow][cs + k] = v[k];
  }
  __syncthreads();
#pragma unroll
  for (int rnd = 0; rnd < 2; ++rnd) {
    int drow = rl + rnd * 32;
    u16x8 o;
#pragma unroll
    for (int k = 0; k < 8; ++k) o[k] = t[cs + k][drow];
    *(u16x8*)&Vt[((size_t)(b * 8 + hk) * 128 + d0 + drow) * 2048 + s0 + cs] = o;
  }
}

// ---------------- Flash attention, causal, GQA(2), softmax sink (+exp(-m)) ----------------
// One q-tile per block (qt = 31 - blockIdx.x: heavy tiles dispatch first, light backfill).
// Single-buffer K/V (dbuf measured neutral) -> 40KB LDS -> 4 blocks/CU = 16 waves/CU.
// VALU-trimmed: native bf16 casts, T13 defer-max, deferred row-sum, T5 setprio on MFMA.
__global__ __launch_bounds__(256) void k_attn(const u16* __restrict__ Qr, const u16* __restrict__ Kr,
                                              const u16* __restrict__ Vt, u16* __restrict__ Og) {
  const int S = 2048;
  __shared__ __align__(16) u16 lK[64 * 128];   // [key][d], swizzled
  __shared__ __align__(16) u16 lV[128 * 64];   // [d][key], swizzled
  __shared__ __align__(16) u16 lP[4][16 * 64]; // per-wave [q][key], swizzled
  int h = blockIdx.y, b = blockIdx.z;
  int hk = h >> 1;
  int tid = threadIdx.x, wid = tid >> 6, lane = tid & 63;
  int fr = lane & 15, fg = lane >> 4;
  const size_t kvbase = ((size_t)(b * 8 + hk)) * S * 128;
  int ksr = tid >> 4, ksc = (tid & 15) * 8;
  int vsr = tid >> 3, vsc = (tid & 7) * 8;
  int kswz = ksc ^ ((ksr & 7) << 3);           // source-side pre-swizzle (involution)
  int vswz = vsc ^ ((vsr & 7) << 3);

  int qt = 31 - (int)blockIdx.x;               // heavy tile first
  int q0 = qt * 64;
  int qw = q0 + wid * 16;
  bf16x8 qf[4];
  {
    const u16* qb = Qr + (((size_t)(b * 16 + h)) * S + qw) * 128;
#pragma unroll
    for (int ds = 0; ds < 4; ++ds)
      qf[ds] = *(const bf16x8*)&qb[fr * 128 + ds * 32 + fg * 8];
  }
  f32x4 acc[8] = {};
  float mR[4] = {-1e30f, -1e30f, -1e30f, -1e30f};
  float lRp[4] = {0.f, 0.f, 0.f, 0.f};   // per-lane partial row sums (reduced in epilogue)
  int nt = qt + 1;
  for (int t = 0; t < nt; ++t) {
    int k0 = t * 64;
#pragma unroll
    for (int r = 0; r < 4; ++r) {
      GLOAD16(&Kr[kvbase + (size_t)(k0 + ksr + r * 16) * 128 + kswz], &lK[(ksr + r * 16) * 128 + ksc]);
      GLOAD16(&Vt[kvbase + (size_t)(vsr + r * 32) * S + k0 + vswz], &lV[(vsr + r * 32) * 64 + vsc]);
    }
    __syncthreads();                       // staged data visible (vmcnt drained)
    f32x4 sf[4] = {};
    __builtin_amdgcn_s_setprio(1);
#pragma unroll
    for (int kb = 0; kb < 4; ++kb)
#pragma unroll
      for (int ds = 0; ds < 4; ++ds) {
        int row = kb * 16 + fr;
        bf16x8 kf = *(const bf16x8*)&lK[row * 128 + ((ds * 32 + fg * 8) ^ ((row & 7) << 3))];
        sf[kb] = __builtin_amdgcn_mfma_f32_16x16x32_bf16(qf[ds], kf, sf[kb], 0, 0, 0);
      }
    __builtin_amdgcn_s_setprio(0);
    if (k0 + 63 > qw) {
#pragma unroll
      for (int kb = 0; kb < 4; ++kb)
#pragma unroll
        for (int r = 0; r < 4; ++r)
          if (k0 + kb * 16 + fr > qw + fg * 4 + r) sf[kb][r] = -1e30f;
    }
    float pm[4];
#pragma unroll
    for (int r = 0; r < 4; ++r) {
      float v = fmaxf(fmaxf(sf[0][r], sf[1][r]), fmaxf(sf[2][r], sf[3][r]));
      v = fmaxf(v, __shfl_xor(v, 1));
      v = fmaxf(v, __shfl_xor(v, 2));
      v = fmaxf(v, __shfl_xor(v, 4));
      v = fmaxf(v, __shfl_xor(v, 8));
      pm[r] = v;
    }
    // T13 defer-max: only rescale when some row's tile-max grew past mR+8.
    bool grow = (pm[0] > mR[0] + 8.f) | (pm[1] > mR[1] + 8.f) |
                (pm[2] > mR[2] + 8.f) | (pm[3] > mR[3] + 8.f);
    if (__any(grow)) {
#pragma unroll
      for (int r = 0; r < 4; ++r) {
        float mn = fmaxf(mR[r], pm[r]);
        float sc = __expf(mR[r] - mn);
        mR[r] = mn;
        lRp[r] *= sc;
#pragma unroll
        for (int ni = 0; ni < 8; ++ni) acc[ni][r] *= sc;
      }
    }
#pragma unroll
    for (int kb = 0; kb < 4; ++kb)
#pragma unroll
      for (int r = 0; r < 4; ++r)
        sf[kb][r] = __expf(sf[kb][r] - mR[r]);
#pragma unroll
    for (int r = 0; r < 4; ++r)
      lRp[r] += (sf[0][r] + sf[1][r]) + (sf[2][r] + sf[3][r]);
#pragma unroll
    for (int kb = 0; kb < 4; ++kb)
#pragma unroll
      for (int r = 0; r < 4; ++r) {
        int q = fg * 4 + r;
        int cu = kb * 16 + fr;
        lP[wid][q * 64 + (cu ^ ((q & 7) << 3))] = __builtin_bit_cast(u16, (__bf16)sf[kb][r]);
      }
    __builtin_amdgcn_s_setprio(1);
#pragma unroll
    for (int kh = 0; kh < 2; ++kh) {
      bf16x8 pf = *(const bf16x8*)&lP[wid][fr * 64 + ((kh * 32 + fg * 8) ^ ((fr & 7) << 3))];
#pragma unroll
      for (int ni = 0; ni < 8; ++ni) {
        int row = ni * 16 + fr;
        bf16x8 vf = *(const bf16x8*)&lV[row * 64 + ((kh * 32 + fg * 8) ^ ((row & 7) << 3))];
        acc[ni] = __builtin_amdgcn_mfma_f32_16x16x32_bf16(pf, vf, acc[ni], 0, 0, 0);
      }
    }
    __builtin_amdgcn_s_setprio(0);
    __syncthreads();                       // all reads done before next tile's stage overwrites
  }
  float rden[4];
#pragma unroll
  for (int r = 0; r < 4; ++r) {
    float s = lRp[r];
    s += __shfl_xor(s, 1);
    s += __shfl_xor(s, 2);
    s += __shfl_xor(s, 4);
    s += __shfl_xor(s, 8);
    rden[r] = 1.0f / (s + __expf(-mR[r]));
  }
#pragma unroll
  for (int ni = 0; ni < 8; ++ni)
#pragma unroll
    for (int r = 0; r < 4; ++r) {
      int q = qw + fg * 4 + r;
      int col = h * 128 + ni * 16 + fr;
      Og[((size_t)(b * S + q)) * 2048 + col] = f2bf(acc[ni][r] * rden[r]);
    }
}

extern "C" void kernel_launch(void* const* d_in, const int* in_sizes, int n_in,
                              void* d_out, int out_size, void* d_ws, size_t ws_size,
                              hipStream_t stream) {
  const float* x  = (const float*)d_in[0];
  const float* fc = (const float*)d_in[1];
  const float* fs = (const float*)d_in[2];
  const float* wq = (const float*)d_in[3];
  const float* wk = (const float*)d_in[4];
  const float* wv = (const float*)d_in[5];
  const float* wo = (const float*)d_in[6];

  char* p = (char*)d_ws;
  u16* xb    = (u16*)p; p += (size_t)4096 * 2048 * 2;   // x bf16 (reused as Og after GEMM1)
  u16* wqkvt = (u16*)p; p += (size_t)4096 * 2048 * 2;   // [wq|wk|wv]^T, N-major 4096x2048
  u16* wot   = (u16*)p; p += (size_t)2048 * 2048 * 2;   // wo^T, 2048x2048
  u16* qkv   = (u16*)p; p += (size_t)4096 * 4096 * 2;   // fused projection output
  u16* Qr    = (u16*)p; p += (size_t)2 * 16 * 2048 * 128 * 2;
  u16* Kr    = (u16*)p; p += (size_t)2 * 8 * 2048 * 128 * 2;
  u16* Vt    = (u16*)p; p += (size_t)2 * 8 * 2048 * 128 * 2;
  u16* Og    = xb;  // alias: xb dead after GEMM1

  k_cvt<<<8192, 256, 0, stream>>>(x, xb, 2097152);
  k_cvt_t<<<dim3(32, 32), 256, 0, stream>>>(wq, wqkvt, 2048, 2048);
  k_cvt_t<<<dim3(16, 32), 256, 0, stream>>>(wk, wqkvt + (size_t)2048 * 2048, 2048, 1024);
  k_cvt_t<<<dim3(16, 32), 256, 0, stream>>>(wv, wqkvt + (size_t)3072 * 2048, 2048, 1024);
  k_cvt_t<<<dim3(32, 32), 256, 0, stream>>>(wo, wot, 2048, 2048);
  k_gemm<false><<<dim3(32, 32), 256, 0, stream>>>(xb, wqkvt, qkv, 4096, 4096, 2048);
  k_rope<<<4096, 256, 0, stream>>>(qkv, fc, fs, Qr, Kr);
  k_vtrans<<<dim3(2, 32, 16), 256, 0, stream>>>(qkv, Vt);
  k_attn<<<dim3(32, 16, 2), 256, 0, stream>>>(Qr, Kr, Vt, Og);
  k_gemm<true><<<dim3(32, 16), 256, 0, stream>>>(Og, wot, d_out, 4096, 2048, 2048);
}

// Round 11
// 355.451 us; speedup vs baseline: 1.2086x; 1.2086x over previous
//
#include <hip/hip_runtime.h>

typedef unsigned short u16;
typedef u16 u16x8 __attribute__((ext_vector_type(8)));
typedef u16 u16x4 __attribute__((ext_vector_type(4)));
typedef unsigned u32x4 __attribute__((ext_vector_type(4)));
typedef __bf16 bf16x8 __attribute__((ext_vector_type(8)));
typedef float f32x4 __attribute__((ext_vector_type(4)));

__device__ __forceinline__ u16 f2bf(float x) {
  unsigned u = __builtin_bit_cast(unsigned, x);
  u = (u + 0x7FFFu + ((u >> 16) & 1u)) >> 16;
  return (u16)u;
}

#define GLOAD16(gp, lp)                                                        \
  __builtin_amdgcn_global_load_lds(                                            \
      (const __attribute__((address_space(1))) unsigned int*)(gp),             \
      (__attribute__((address_space(3))) unsigned int*)(lp), 16, 0, 0)

// ---------------- f32 -> bf16 convert (vectorized) ----------------
__global__ __launch_bounds__(256) void k_cvt(const float* __restrict__ in, u16* __restrict__ out, int n4) {
  int i = blockIdx.x * 256 + threadIdx.x;
  if (i >= n4) return;
  float4 v = ((const float4*)in)[i];
  u16x4 o;
  o[0] = f2bf(v.x); o[1] = f2bf(v.y); o[2] = f2bf(v.z); o[3] = f2bf(v.w);
  ((u16x4*)out)[i] = o;
}

// ---------------- f32 -> bf16 convert + transpose: out[c][r] = in[r][c], out row stride R ----------------
__global__ __launch_bounds__(256) void k_cvt_t(const float* __restrict__ in, u16* __restrict__ out, int R, int C) {
  __shared__ u16 t[64][72];
  int c0 = blockIdx.x * 64, r0 = blockIdx.y * 64;
  int tid = threadIdx.x;
  int rl = tid >> 2;          // 0..63
  int cl0 = (tid & 3) * 16;   // 0,16,32,48
#pragma unroll
  for (int j = 0; j < 4; ++j) {
    float4 v = *(const float4*)&in[(size_t)(r0 + rl) * C + c0 + cl0 + j * 4];
    t[rl][cl0 + j * 4 + 0] = f2bf(v.x);
    t[rl][cl0 + j * 4 + 1] = f2bf(v.y);
    t[rl][cl0 + j * 4 + 2] = f2bf(v.z);
    t[rl][cl0 + j * 4 + 3] = f2bf(v.w);
  }
  __syncthreads();
  int cr = tid >> 2;          // out row (c) 0..63
  int s0 = (tid & 3) * 16;    // r offset
  __align__(16) u16 tmp[16];
#pragma unroll
  for (int k = 0; k < 16; ++k) tmp[k] = t[s0 + k][cr];
  *(u16x8*)&out[(size_t)(c0 + cr) * R + r0 + s0]     = *(u16x8*)&tmp[0];
  *(u16x8*)&out[(size_t)(c0 + cr) * R + r0 + s0 + 8] = *(u16x8*)&tmp[8];
}

// ---------------- bf16 GEMM: C = A(MxK) * B(KxN), Bt given as N-major (NxK). 128x128 tile, BK=64 ----------------
template <bool F32OUT>
__global__ __launch_bounds__(256) void k_gemm(const u16* __restrict__ A, const u16* __restrict__ Bt,
                                              void* __restrict__ Cout, int M, int N, int K) {
  __shared__ __align__(16) u16 lA[128 * 64];
  __shared__ __align__(16) u16 lB[128 * 64];
  int m0 = blockIdx.x * 128, n0 = blockIdx.y * 128;
  int tid = threadIdx.x;
  int wid = tid >> 6, lane = tid & 63;
  int fr = lane & 15, fg = lane >> 4;
  int wm = (wid & 1) * 64, wn = (wid >> 1) * 64;
  int srow = tid >> 3, scu = (tid & 7) * 8;
  f32x4 acc[4][4] = {};
  const int nk = K >> 6;
  for (int kt = 0; kt < nk; ++kt) {
    int k0 = kt << 6;
#pragma unroll
    for (int r = 0; r < 4; ++r) {
      int row = srow + r * 32;
      int swz = scu ^ ((row & 7) << 3);
      GLOAD16(&A[(size_t)(m0 + row) * K + k0 + swz],  &lA[row * 64 + scu]);
      GLOAD16(&Bt[(size_t)(n0 + row) * K + k0 + swz], &lB[row * 64 + scu]);
    }
    __syncthreads();
#pragma unroll
    for (int kh = 0; kh < 2; ++kh) {
      bf16x8 af[4], bf[4];
#pragma unroll
      for (int mi = 0; mi < 4; ++mi) {
        int row = wm + mi * 16 + fr;
        af[mi] = *(const bf16x8*)&lA[row * 64 + ((kh * 32 + fg * 8) ^ ((row & 7) << 3))];
      }
#pragma unroll
      for (int ni = 0; ni < 4; ++ni) {
        int row = wn + ni * 16 + fr;
        bf[ni] = *(const bf16x8*)&lB[row * 64 + ((kh * 32 + fg * 8) ^ ((row & 7) << 3))];
      }
#pragma unroll
      for (int mi = 0; mi < 4; ++mi)
#pragma unroll
        for (int ni = 0; ni < 4; ++ni)
          acc[mi][ni] = __builtin_amdgcn_mfma_f32_16x16x32_bf16(af[mi], bf[ni], acc[mi][ni], 0, 0, 0);
    }
    __syncthreads();
  }
#pragma unroll
  for (int mi = 0; mi < 4; ++mi)
#pragma unroll
    for (int ni = 0; ni < 4; ++ni)
#pragma unroll
      for (int r = 0; r < 4; ++r) {
        int row = m0 + wm + mi * 16 + fg * 4 + r;
        int col = n0 + wn + ni * 16 + fr;
        float v = acc[mi][ni][r];
        if (F32OUT) ((float*)Cout)[(size_t)row * N + col] = v;
        else        ((u16*)Cout)[(size_t)row * N + col] = f2bf(v);
      }
}

// ---------------- RoPE on Q (with 1/sqrt(HD) pre-scale) and K; writes head-major layouts ----------------
__global__ __launch_bounds__(256) void k_rope(const u16* __restrict__ qkv, const float* __restrict__ fc,
                                              const float* __restrict__ fs, u16* __restrict__ Qr,
                                              u16* __restrict__ Kr) {
  int row = blockIdx.x;           // b*2048 + s
  int b = row >> 11, s = row & 2047;
  int tid = threadIdx.x;
  float4 c4 = *(const float4*)&fc[s * 64 + (tid & 15) * 4];
  float4 s4 = *(const float4*)&fs[s * 64 + (tid & 15) * 4];
  float cc[4] = {c4.x, c4.y, c4.z, c4.w};
  float ss[4] = {s4.x, s4.y, s4.z, s4.w};
  {
    bf16x8 v = *(const bf16x8*)&qkv[(size_t)row * 4096 + tid * 8];
    bf16x8 o;
    const float qs = 0.08838834764831845f;  // 1/sqrt(128)
#pragma unroll
    for (int j = 0; j < 4; ++j) {
      float e = (float)v[2 * j], od = (float)v[2 * j + 1];
      o[2 * j]     = (__bf16)((e * cc[j] - od * ss[j]) * qs);
      o[2 * j + 1] = (__bf16)((e * ss[j] + od * cc[j]) * qs);
    }
    int h = tid >> 4, d0 = (tid & 15) * 8;
    *(bf16x8*)&Qr[(((size_t)(b * 16 + h)) * 2048 + s) * 128 + d0] = o;
  }
  if (tid < 128) {
    bf16x8 v = *(const bf16x8*)&qkv[(size_t)row * 4096 + 2048 + tid * 8];
    bf16x8 o;
#pragma unroll
    for (int j = 0; j < 4; ++j) {
      float e = (float)v[2 * j], od = (float)v[2 * j + 1];
      o[2 * j]     = (__bf16)(e * cc[j] - od * ss[j]);
      o[2 * j + 1] = (__bf16)(e * ss[j] + od * cc[j]);
    }
    int hk = tid >> 4, d0 = (tid & 15) * 8;
    *(bf16x8*)&Kr[(((size_t)(b * 8 + hk)) * 2048 + s) * 128 + d0] = o;
  }
}

// ---------------- V transpose: Vt[b][hk][d][s] = qkv[b*S+s][3072 + hk*128 + d] ----------------
__global__ __launch_bounds__(256) void k_vtrans(const u16* __restrict__ qkv, u16* __restrict__ Vt) {
  __shared__ u16 t[64][72];
  int dt = blockIdx.x, st = blockIdx.y, bh = blockIdx.z;
  int b = bh >> 3, hk = bh & 7;
  int s0 = st * 64, d0 = dt * 64;
  int tid = threadIdx.x;
  int rl = tid >> 3, cs = (tid & 7) * 8;
#pragma unroll
  for (int rnd = 0; rnd < 2; ++rnd) {
    int srow = rl + rnd * 32;
    u16x8 v = *(const u16x8*)&qkv[(size_t)(b * 2048 + s0 + srow) * 4096 + 3072 + hk * 128 + d0 + cs];
#pragma unroll
    for (int k = 0; k < 8; ++k) t[srow][cs + k] = v[k];
  }
  __syncthreads();
#pragma unroll
  for (int rnd = 0; rnd < 2; ++rnd) {
    int drow = rl + rnd * 32;
    u16x8 o;
#pragma unroll
    for (int k = 0; k < 8; ++k) o[k] = t[cs + k][drow];
    *(u16x8*)&Vt[((size_t)(b * 8 + hk) * 128 + d0 + drow) * 2048 + s0 + cs] = o;
  }
}

// ---------------- Flash attention, causal, GQA(2), softmax sink (+exp(-m)) ----------------
// Round-7 shell (paired 512 blocks, dbuf K/V) + SWAPPED QK^T: sf = mfma(K, Q) puts the full
// softmax row in-lane (q = fr), so mR/lRp are scalars and P never touches LDS: the PV
// A-fragment is built with 16 register __shfl of packed-bf16 dwords (lP deleted; 64KB LDS).
__global__ __launch_bounds__(256) void k_attn(const u16* __restrict__ Qr, const u16* __restrict__ Kr,
                                              const u16* __restrict__ Vt, u16* __restrict__ Og) {
  const int S = 2048;
  __shared__ __align__(16) u16 lK[2][64 * 128];   // [key][d], swizzled
  __shared__ __align__(16) u16 lV[2][128 * 64];   // [d][key], swizzled
  int h = blockIdx.y, b = blockIdx.z;
  int hk = h >> 1;
  int tid = threadIdx.x, wid = tid >> 6, lane = tid & 63;
  int fr = lane & 15, fg = lane >> 4;
  const size_t kvbase = ((size_t)(b * 8 + hk)) * S * 128;
  int ksr = tid >> 4, ksc = (tid & 15) * 8;
  int vsr = tid >> 3, vsc = (tid & 7) * 8;
  int kswz = ksc ^ ((ksr & 7) << 3);           // source-side pre-swizzle (involution)
  int vswz = vsc ^ ((vsr & 7) << 3);

#define STAGE_KV(K0, BUF)                                                                      \
  {                                                                                            \
    int k0_ = (K0);                                                                            \
    _Pragma("unroll")                                                                          \
    for (int r = 0; r < 4; ++r) {                                                              \
      GLOAD16(&Kr[kvbase + (size_t)(k0_ + ksr + r * 16) * 128 + kswz],                         \
              &lK[BUF][(ksr + r * 16) * 128 + ksc]);                                           \
      GLOAD16(&Vt[kvbase + (size_t)(vsr + r * 32) * S + k0_ + vswz],                           \
              &lV[BUF][(vsr + r * 32) * 64 + vsc]);                                            \
    }                                                                                          \
  }

  for (int pp = 0; pp < 2; ++pp) {
    int qt = pp == 0 ? (31 - (int)blockIdx.x) : (int)blockIdx.x;  // heavy tile first
    int q0 = qt * 64;
    int qw = q0 + wid * 16;
    bf16x8 qf[4];
    {
      const u16* qb = Qr + (((size_t)(b * 16 + h)) * S + qw) * 128;
#pragma unroll
      for (int ds = 0; ds < 4; ++ds)
        qf[ds] = *(const bf16x8*)&qb[fr * 128 + ds * 32 + fg * 8];
    }
    f32x4 acc[8] = {};
    float mR = -1e30f;   // running max for q = qw + fr (lane-local row!)
    float lRp = 0.f;     // lane-partial row sum for q = qw + fr
    int nt = qt + 1;
    STAGE_KV(0, 0);
    __syncthreads();
    int cur = 0;
    for (int t = 0; t < nt; ++t) {
      int k0 = t * 64;
      if (t + 1 < nt) STAGE_KV(k0 + 64, cur ^ 1);   // prefetch next tile
      f32x4 sf[4] = {};
      __builtin_amdgcn_s_setprio(1);
#pragma unroll
      for (int kb = 0; kb < 4; ++kb)
#pragma unroll
        for (int ds = 0; ds < 4; ++ds) {
          int row = kb * 16 + fr;
          bf16x8 kf = *(const bf16x8*)&lK[cur][row * 128 + ((ds * 32 + fg * 8) ^ ((row & 7) << 3))];
          // SWAPPED: A=K, B=Q  ->  sf[kb][r] = S[key = k0+kb*16+fg*4+r][q = qw+fr]
          sf[kb] = __builtin_amdgcn_mfma_f32_16x16x32_bf16(kf, qf[ds], sf[kb], 0, 0, 0);
        }
      __builtin_amdgcn_s_setprio(0);
      if (k0 + 63 > qw) {
#pragma unroll
        for (int kb = 0; kb < 4; ++kb)
#pragma unroll
          for (int r = 0; r < 4; ++r)
            if (k0 + kb * 16 + fg * 4 + r > qw + fr) sf[kb][r] = -1e30f;
      }
      // tile max for this lane's row (q = qw+fr): in-lane 16 + cross-fg reduce
      float pm;
      {
        float v0 = fmaxf(fmaxf(sf[0][0], sf[0][1]), fmaxf(sf[0][2], sf[0][3]));
        float v1 = fmaxf(fmaxf(sf[1][0], sf[1][1]), fmaxf(sf[1][2], sf[1][3]));
        float v2 = fmaxf(fmaxf(sf[2][0], sf[2][1]), fmaxf(sf[2][2], sf[2][3]));
        float v3 = fmaxf(fmaxf(sf[3][0], sf[3][1]), fmaxf(sf[3][2], sf[3][3]));
        pm = fmaxf(fmaxf(v0, v1), fmaxf(v2, v3));
        pm = fmaxf(pm, __shfl_xor(pm, 16));
        pm = fmaxf(pm, __shfl_xor(pm, 32));
      }
      // T13 defer-max
      if (__any(pm > mR + 8.f)) {
        float mn = fmaxf(mR, pm);
        float sc = __expf(mR - mn);
        mR = mn;
        lRp *= sc;
        float sc4[4];
#pragma unroll
        for (int r = 0; r < 4; ++r) sc4[r] = __shfl(sc, fg * 4 + r);  // sc for q_out = qw+fg*4+r
#pragma unroll
        for (int ni = 0; ni < 8; ++ni)
#pragma unroll
          for (int r = 0; r < 4; ++r) acc[ni][r] *= sc4[r];
      }
#pragma unroll
      for (int kb = 0; kb < 4; ++kb)
#pragma unroll
        for (int r = 0; r < 4; ++r)
          sf[kb][r] = __expf(sf[kb][r] - mR);
      lRp += ((sf[0][0] + sf[0][1] + sf[0][2] + sf[0][3]) + (sf[1][0] + sf[1][1] + sf[1][2] + sf[1][3]))
           + ((sf[2][0] + sf[2][1] + sf[2][2] + sf[2][3]) + (sf[3][0] + sf[3][1] + sf[3][2] + sf[3][3]));
      // pack P rows to bf16 dwords: pk[kb][h] = keys (fg*4+2h, fg*4+2h+1) of q=fr
      unsigned pk[4][2];
#pragma unroll
      for (int kb = 0; kb < 4; ++kb)
#pragma unroll
        for (int hh = 0; hh < 2; ++hh) {
          unsigned lo = (unsigned)__builtin_bit_cast(u16, (__bf16)sf[kb][2 * hh]);
          unsigned hi = (unsigned)__builtin_bit_cast(u16, (__bf16)sf[kb][2 * hh + 1]);
          pk[kb][hh] = lo | (hi << 16);
        }
      __builtin_amdgcn_s_setprio(1);
#pragma unroll
      for (int kh = 0; kh < 2; ++kh) {
        // build A-fragment P[q=fr][key = k0 + kh*32 + fg*8 + 0..7] from registers
        unsigned dw[4];
#pragma unroll
        for (int d = 0; d < 4; ++d) {
          int src = ((2 * (fg & 1) + (d >> 1)) << 4) + fr;
          unsigned a = (unsigned)__shfl((int)pk[2 * kh][d & 1], src);
          unsigned bsel = (unsigned)__shfl((int)pk[2 * kh + 1][d & 1], src);
          dw[d] = (fg & 2) ? bsel : a;
        }
        u32x4 dwv = {dw[0], dw[1], dw[2], dw[3]};
        bf16x8 pf = __builtin_bit_cast(bf16x8, dwv);
#pragma unroll
        for (int ni = 0; ni < 8; ++ni) {
          int row = ni * 16 + fr;
          bf16x8 vf = *(const bf16x8*)&lV[cur][row * 64 + ((kh * 32 + fg * 8) ^ ((row & 7) << 3))];
          acc[ni] = __builtin_amdgcn_mfma_f32_16x16x32_bf16(pf, vf, acc[ni], 0, 0, 0);
        }
      }
      __builtin_amdgcn_s_setprio(0);
      __syncthreads();   // prefetch landed during compute; reads done before next stage
      cur ^= 1;
    }
    // epilogue: finish row sum for q=fr, then gather per-acc-row factors
    float s = lRp;
    s += __shfl_xor(s, 16);
    s += __shfl_xor(s, 32);
    float rden = 1.0f / (s + __expf(-mR));
    float rd4[4];
#pragma unroll
    for (int r = 0; r < 4; ++r) rd4[r] = __shfl(rden, fg * 4 + r);
#pragma unroll
    for (int ni = 0; ni < 8; ++ni)
#pragma unroll
      for (int r = 0; r < 4; ++r) {
        int q = qw + fg * 4 + r;
        int col = h * 128 + ni * 16 + fr;
        Og[((size_t)(b * S + q)) * 2048 + col] = f2bf(acc[ni][r] * rd4[r]);
      }
  }
#undef STAGE_KV
}

extern "C" void kernel_launch(void* const* d_in, const int* in_sizes, int n_in,
                              void* d_out, int out_size, void* d_ws, size_t ws_size,
                              hipStream_t stream) {
  const float* x  = (const float*)d_in[0];
  const float* fc = (const float*)d_in[1];
  const float* fs = (const float*)d_in[2];
  const float* wq = (const float*)d_in[3];
  const float* wk = (const float*)d_in[4];
  const float* wv = (const float*)d_in[5];
  const float* wo = (const float*)d_in[6];

  char* p = (char*)d_ws;
  u16* xb    = (u16*)p; p += (size_t)4096 * 2048 * 2;   // x bf16 (reused as Og after GEMM1)
  u16* wqkvt = (u16*)p; p += (size_t)4096 * 2048 * 2;   // [wq|wk|wv]^T, N-major 4096x2048
  u16* wot   = (u16*)p; p += (size_t)2048 * 2048 * 2;   // wo^T, 2048x2048
  u16* qkv   = (u16*)p; p += (size_t)4096 * 4096 * 2;   // fused projection output
  u16* Qr    = (u16*)p; p += (size_t)2 * 16 * 2048 * 128 * 2;
  u16* Kr    = (u16*)p; p += (size_t)2 * 8 * 2048 * 128 * 2;
  u16* Vt    = (u16*)p; p += (size_t)2 * 8 * 2048 * 128 * 2;
  u16* Og    = xb;  // alias: xb dead after GEMM1

  k_cvt<<<8192, 256, 0, stream>>>(x, xb, 2097152);
  k_cvt_t<<<dim3(32, 32), 256, 0, stream>>>(wq, wqkvt, 2048, 2048);
  k_cvt_t<<<dim3(16, 32), 256, 0, stream>>>(wk, wqkvt + (size_t)2048 * 2048, 2048, 1024);
  k_cvt_t<<<dim3(16, 32), 256, 0, stream>>>(wv, wqkvt + (size_t)3072 * 2048, 2048, 1024);
  k_cvt_t<<<dim3(32, 32), 256, 0, stream>>>(wo, wot, 2048, 2048);
  k_gemm<false><<<dim3(32, 32), 256, 0, stream>>>(xb, wqkvt, qkv, 4096, 4096, 2048);
  k_rope<<<4096, 256, 0, stream>>>(qkv, fc, fs, Qr, Kr);
  k_vtrans<<<dim3(2, 32, 16), 256, 0, stream>>>(qkv, Vt);
  k_attn<<<dim3(16, 16, 2), 256, 0, stream>>>(Qr, Kr, Vt, Og);
  k_gemm<true><<<dim3(32, 16), 256, 0, stream>>>(Og, wot, d_out, 4096, 2048, 2048);
}